// Round 6
// baseline (742.763 us; speedup 1.0000x reference)
//
#include <hip/hip_runtime.h>

#define DIM   64
#define G3    192      // 3*DIM
#define NB    512      // BATCH
#define NM    32       // N_MEM
#define NRELS 32
#define KGE_W 0.01f
#define L2_W  1e-7f
#define EPSC  1e-7f

// ---------- helpers ----------

__device__ inline float bcast(float v, int srclane) {
    return __int_as_float(__builtin_amdgcn_readlane(__float_as_int(v), srclane));
}

__device__ inline float sigmoidf_(float x) { return 1.0f / (1.0f + __expf(-x)); }
__device__ inline float tanhf_(float x)    { return 1.0f - 2.0f / (1.0f + __expf(2.0f * x)); }

__device__ inline float wave_sum(float v) {
#pragma unroll
    for (int off = 32; off > 0; off >>= 1) v += __shfl_xor(v, off, 64);
    return v;
}
__device__ inline float wave_max(float v) {
#pragma unroll
    for (int off = 32; off > 0; off >>= 1) v = fmaxf(v, __shfl_xor(v, off, 64));
    return v;
}

// ---------- GRU kernel: 4 waves, k-split (48 weights/lane), ys in LDS ----------
// Wave w owns k-slice [16w,16w+16) of the 192x64 matvec; partial sums are
// exchanged via double-buffered LDS slots (one __syncthreads per step).
// ys accumulates in LDS (no global stores in the loop -> the barrier's
// vmcnt(0) drain has nothing to wait on except distance-4 GI prefetch loads
// that are already a full iteration old). Gates computed redundantly in all
// waves so h stays replicated in registers.

__global__ __launch_bounds__(256, 1) void gru_kernel(const float* __restrict__ GI,   // [NB][192]
                                                     const float* __restrict__ whh,  // [192][64]
                                                     const float* __restrict__ bhh,  // [192]
                                                     const float* __restrict__ h0,   // [64] or nullptr
                                                     float* __restrict__ ys,         // [NB][64]
                                                     float* __restrict__ hfin_out)   // [64] or nullptr
{
    __shared__ float ysl[NB][DIM];          // 128 KiB
    __shared__ float part[2][4][3][DIM];    // 6 KiB: [slot][wave][gate][row]

    const int tid  = threadIdx.x;
    const int lane = tid & 63;
    const int wave = tid >> 6;
    const int k0   = wave * 16;

    // weights: rows {lane, 64+lane, 128+lane}, cols [k0, k0+16)
    float wr[16], wz[16], wn[16];
#pragma unroll
    for (int i = 0; i < 16; ++i) {
        wr[i] = whh[(0 * DIM + lane) * DIM + k0 + i];
        wz[i] = whh[(1 * DIM + lane) * DIM + k0 + i];
        wn[i] = whh[(2 * DIM + lane) * DIM + k0 + i];
    }
    const float br = bhh[lane], bz = bhh[DIM + lane], bn = bhh[2 * DIM + lane];

    float h = h0 ? h0[lane] : 0.0f;

    // GI pipeline distance 4: c=t, d=t+1, e=t+2, f=t+3
    float c0 = GI[0*G3 + lane], c1 = GI[0*G3 + DIM + lane], c2 = GI[0*G3 + 2*DIM + lane];
    float d0 = GI[1*G3 + lane], d1 = GI[1*G3 + DIM + lane], d2 = GI[1*G3 + 2*DIM + lane];
    float e0 = GI[2*G3 + lane], e1 = GI[2*G3 + DIM + lane], e2 = GI[2*G3 + 2*DIM + lane];
    float f0 = GI[3*G3 + lane], f1 = GI[3*G3 + DIM + lane], f2 = GI[3*G3 + 2*DIM + lane];

    for (int t = 0; t < NB; t += 2) {
        // ===== even step t (slot 0), consumes c =====
        {
            float pr = 0.f, pz = 0.f, pn = 0.f;
#pragma unroll
            for (int i = 0; i < 16; ++i) {
                float hk = bcast(h, k0 + i);
                pr = fmaf(wr[i], hk, pr); pz = fmaf(wz[i], hk, pz); pn = fmaf(wn[i], hk, pn);
            }
            part[0][wave][0][lane] = pr;
            part[0][wave][1][lane] = pz;
            part[0][wave][2][lane] = pn;
            __syncthreads();

            // post-barrier: issue GI loads for t+4 (a full step before next drain)
            const int tp = (t + 4 < NB) ? t + 4 : NB - 1;
            const float* gp = GI + tp * G3;
            float g0 = gp[lane], g1 = gp[DIM + lane], g2 = gp[2 * DIM + lane];

            float ghr = br, ghz = bz, ghn = bn;
#pragma unroll
            for (int w = 0; w < 4; ++w) {
                ghr += part[0][w][0][lane];
                ghz += part[0][w][1][lane];
                ghn += part[0][w][2][lane];
            }
            float r = sigmoidf_(c0 + ghr);
            float z = sigmoidf_(c1 + ghz);
            float n = tanhf_(c2 + r * ghn);
            h = n + z * (h - n);               // (1-z)*n + z*h
            if (wave == 0) ysl[t][lane] = h;

            c0 = d0; c1 = d1; c2 = d2;
            d0 = e0; d1 = e1; d2 = e2;
            e0 = f0; e1 = f1; e2 = f2;
            f0 = g0; f1 = g1; f2 = g2;
        }
        // ===== odd step t+1 (slot 1), consumes c (rotated) =====
        {
            float pr = 0.f, pz = 0.f, pn = 0.f;
#pragma unroll
            for (int i = 0; i < 16; ++i) {
                float hk = bcast(h, k0 + i);
                pr = fmaf(wr[i], hk, pr); pz = fmaf(wz[i], hk, pz); pn = fmaf(wn[i], hk, pn);
            }
            part[1][wave][0][lane] = pr;
            part[1][wave][1][lane] = pz;
            part[1][wave][2][lane] = pn;
            __syncthreads();

            const int tp = (t + 5 < NB) ? t + 5 : NB - 1;
            const float* gp = GI + tp * G3;
            float g0 = gp[lane], g1 = gp[DIM + lane], g2 = gp[2 * DIM + lane];

            float ghr = br, ghz = bz, ghn = bn;
#pragma unroll
            for (int w = 0; w < 4; ++w) {
                ghr += part[1][w][0][lane];
                ghz += part[1][w][1][lane];
                ghn += part[1][w][2][lane];
            }
            float r = sigmoidf_(c0 + ghr);
            float z = sigmoidf_(c1 + ghz);
            float n = tanhf_(c2 + r * ghn);
            h = n + z * (h - n);
            if (wave == 0) ysl[t + 1][lane] = h;

            c0 = d0; c1 = d1; c2 = d2;
            d0 = e0; d1 = e1; d2 = e2;
            e0 = f0; e1 = f1; e2 = f2;
            f0 = g0; f1 = g1; f2 = g2;
        }
    }
    __syncthreads();

    // flush ysl -> ys, coalesced float4
    float4* ysg = (float4*)ys;
    const float4* ysl4 = (const float4*)ysl;
    for (int i = tid; i < NB * DIM / 4; i += 256) ysg[i] = ysl4[i];

    if (hfin_out && tid < 64) hfin_out[lane] = h;   // h replicated across waves
}

// ---------- gi: GI = wih @ x + bih (+ per-relation sqnorm on extra blocks) ----------

__global__ __launch_bounds__(64) void gi_kernel(const float* __restrict__ xsrc,
                                                const int* __restrict__ idx,    // nullptr => direct
                                                const float* __restrict__ wih,  // [192][64]
                                                const float* __restrict__ bih,  // [192]
                                                const float* __restrict__ Rel,  // [32][4096]
                                                float* __restrict__ GI,         // [NB][192]
                                                float* __restrict__ relnorm)    // [32]
{
    const int blk = blockIdx.x, lane = threadIdx.x;
    if (blk >= NB) {
        const int r = blk - NB;
        const float* R = Rel + r * DIM * DIM;
        float a = 0.0f;
#pragma unroll 4
        for (int i = 0; i < DIM; ++i) { float v = R[i * DIM + lane]; a = fmaf(v, v, a); }
        a = wave_sum(a);
        if (lane == 0) relnorm[r] = a;
        return;
    }
    const int b = blk;
    float xv = idx ? xsrc[idx[b] * DIM + lane] : xsrc[b * DIM + lane];
    float a0 = bih[lane], a1 = bih[DIM + lane], a2 = bih[2 * DIM + lane];
    const float* w0 = wih + (0 * DIM + lane) * DIM;
    const float* w1 = wih + (1 * DIM + lane) * DIM;
    const float* w2 = wih + (2 * DIM + lane) * DIM;
#pragma unroll 4
    for (int k = 0; k < DIM; ++k) {
        float xk = bcast(xv, k);
        a0 = fmaf(w0[k], xk, a0);
        a1 = fmaf(w1[k], xk, a1);
        a2 = fmaf(w2[k], xk, a2);
    }
    float* gp = GI + b * G3;
    gp[lane] = a0; gp[DIM + lane] = a1; gp[2 * DIM + lane] = a2;
}

// ---------- att0: attention hop0 + KGE(both hops) + L2 partials ----------

__global__ __launch_bounds__(256) void att0(const float* __restrict__ E,
                                            const float* __restrict__ Rel,
                                            const int* __restrict__ items,
                                            const int* __restrict__ mh,
                                            const int* __restrict__ mr,
                                            const int* __restrict__ mt,
                                            const float* __restrict__ relnorm,
                                            float* __restrict__ o0,
                                            float* __restrict__ kge_part,   // [NB][2]
                                            float* __restrict__ l2_part)    // [NB]
{
    const int b = blockIdx.x;
    const int tid = threadIdx.x, lane = tid & 63, wave = tid >> 6;
    __shared__ float logits[NM], probs[NM], opart[4][DIM], wred[4][4];

    float iv = E[items[b] * DIM + lane];
    float kge0 = 0.0f, kge1 = 0.0f, l2acc = 0.0f, r2acc = 0.0f;

    for (int mm = 0; mm < 8; ++mm) {
        const int m = wave * 8 + mm;
        const int base = b * NM + m;                 // hop 0
        const int hidx = mh[base], ridx = mr[base], tidx = mt[base];
        float hv = E[hidx * DIM + lane];
        float tv = E[tidx * DIM + lane];
        l2acc = fmaf(hv, hv, l2acc);
        l2acc = fmaf(tv, tv, l2acc);
        r2acc += relnorm[ridx];
        const float* R = Rel + ridx * DIM * DIM;
        float accA = 0.0f, accK = 0.0f;
#pragma unroll 4
        for (int i = 0; i < DIM; ++i) {
            float rv = R[i * DIM + lane];
            accA = fmaf(bcast(iv, i), rv, accA);
            accK = fmaf(bcast(hv, i), rv, accK);
        }
        float la = wave_sum(accA * hv);              // item^T R h
        float lk = wave_sum(accK * tv);              // h^T R t
        if (lane == 0) logits[m] = la;
        kge0 += sigmoidf_(lk);
    }
    for (int mm = 0; mm < 8; ++mm) {
        const int m = wave * 8 + mm;
        const int base = NB * NM + b * NM + m;       // hop 1
        const int hidx = mh[base], ridx = mr[base], tidx = mt[base];
        float hv = E[hidx * DIM + lane];
        float tv = E[tidx * DIM + lane];
        l2acc = fmaf(hv, hv, l2acc);
        l2acc = fmaf(tv, tv, l2acc);
        r2acc += relnorm[ridx];
        const float* R = Rel + ridx * DIM * DIM;
        float accK = 0.0f;
#pragma unroll 4
        for (int i = 0; i < DIM; ++i)
            accK = fmaf(bcast(hv, i), R[i * DIM + lane], accK);
        kge1 += sigmoidf_(wave_sum(accK * tv));
    }
    __syncthreads();

    if (wave == 0) {
        float v = (lane < NM) ? logits[lane] : -1e30f;
        float mx = wave_max(v);
        float e = (lane < NM) ? __expf(v - mx) : 0.0f;
        float ssum = wave_sum(e);
        if (lane < NM) probs[lane] = e / ssum;
    }
    __syncthreads();

    float od = 0.0f;
    for (int mm = 0; mm < 8; ++mm) {
        const int m = wave * 8 + mm;
        const int tidx = mt[b * NM + m];
        od = fmaf(probs[m], E[tidx * DIM + lane], od);
    }
    opart[wave][lane] = od;
    float l2tot = wave_sum(l2acc);
    if (lane == 0) { wred[wave][0] = kge0; wred[wave][1] = kge1; wred[wave][2] = l2tot + r2acc; }
    __syncthreads();
    if (wave == 0)
        o0[b * DIM + lane] = opart[0][lane] + opart[1][lane] + opart[2][lane] + opart[3][lane];
    if (tid == 0) {
        kge_part[b * 2 + 0] = wred[0][0] + wred[1][0] + wred[2][0] + wred[3][0];
        kge_part[b * 2 + 1] = wred[0][1] + wred[1][1] + wred[2][1] + wred[3][1];
        l2_part[b]          = wred[0][2] + wred[1][2] + wred[2][2] + wred[3][2];
    }
}

// ---------- att1: attention hop1 + o_sum (needs ys0) ----------

__global__ __launch_bounds__(256) void att1(const float* __restrict__ E,
                                            const float* __restrict__ Rel,
                                            const int* __restrict__ mh,
                                            const int* __restrict__ mr,
                                            const int* __restrict__ mt,
                                            const float* __restrict__ ys0,
                                            const float* __restrict__ o0,
                                            float* __restrict__ osum)
{
    const int b = blockIdx.x;
    const int tid = threadIdx.x, lane = tid & 63, wave = tid >> 6;
    __shared__ float logits[NM], probs[NM], opart[4][DIM];

    float iv = ys0[b * DIM + lane];   // item_emb after 1 GRU pass

    for (int mm = 0; mm < 8; ++mm) {
        const int m = wave * 8 + mm;
        const int base = NB * NM + b * NM + m;       // hop 1
        const int hidx = mh[base], ridx = mr[base];
        float hv = E[hidx * DIM + lane];
        const float* R = Rel + ridx * DIM * DIM;
        float accA = 0.0f;
#pragma unroll 4
        for (int i = 0; i < DIM; ++i)
            accA = fmaf(bcast(iv, i), R[i * DIM + lane], accA);
        float la = wave_sum(accA * hv);
        if (lane == 0) logits[m] = la;
    }
    __syncthreads();
    if (wave == 0) {
        float v = (lane < NM) ? logits[lane] : -1e30f;
        float mx = wave_max(v);
        float e = (lane < NM) ? __expf(v - mx) : 0.0f;
        float ssum = wave_sum(e);
        if (lane < NM) probs[lane] = e / ssum;
    }
    __syncthreads();
    float od = 0.0f;
    for (int mm = 0; mm < 8; ++mm) {
        const int m = wave * 8 + mm;
        const int tidx = mt[NB * NM + b * NM + m];
        od = fmaf(probs[m], E[tidx * DIM + lane], od);
    }
    opart[wave][lane] = od;
    __syncthreads();
    if (wave == 0)
        osum[b * DIM + lane] = o0[b * DIM + lane] +
            opart[0][lane] + opart[1][lane] + opart[2][lane] + opart[3][lane];
}

// ---------- finalize: scores + losses ----------

__global__ __launch_bounds__(512) void finalize(const float* __restrict__ ys1,
                                                const float* __restrict__ osum,
                                                const int* __restrict__ labels,
                                                const float* __restrict__ kge_part,
                                                const float* __restrict__ l2_part,
                                                float* __restrict__ out)
{
    __shared__ float red[512];
    const int tid = threadIdx.x;

    float dot = 0.0f;
    const float* a = ys1 + tid * DIM;
    const float* c = osum + tid * DIM;
#pragma unroll 8
    for (int k = 0; k < DIM; ++k) dot = fmaf(a[k], c[k], dot);
    float score = sigmoidf_(dot);
    out[tid] = score;

    float s = fminf(fmaxf(score, EPSC), 1.0f - EPSC);
    float term = labels[tid] ? logf(s) : log1pf(-s);

    float bsum, ksum, lsum;
    {
        red[tid] = term; __syncthreads();
#pragma unroll
        for (int st = 256; st > 0; st >>= 1) { if (tid < st) red[tid] += red[tid + st]; __syncthreads(); }
        bsum = red[0]; __syncthreads();
    }
    {
        red[tid] = kge_part[2 * tid] + kge_part[2 * tid + 1]; __syncthreads();
#pragma unroll
        for (int st = 256; st > 0; st >>= 1) { if (tid < st) red[tid] += red[tid + st]; __syncthreads(); }
        ksum = red[0]; __syncthreads();
    }
    {
        red[tid] = l2_part[tid]; __syncthreads();
#pragma unroll
        for (int st = 256; st > 0; st >>= 1) { if (tid < st) red[tid] += red[tid + st]; __syncthreads(); }
        lsum = red[0];
    }

    if (tid == 0) {
        float base = -bsum / (float)NB;
        float kge  = -KGE_W * ksum / (float)(NB * NM);
        float l2   = L2_W * lsum;
        out[NB + 0] = base;
        out[NB + 1] = kge;
        out[NB + 2] = l2;
        out[NB + 3] = base + kge + l2;
    }
}

// ---------- host ----------

extern "C" void kernel_launch(void* const* d_in, const int* in_sizes, int n_in,
                              void* d_out, int out_size, void* d_ws, size_t ws_size,
                              hipStream_t stream) {
    const int*   items  = (const int*)d_in[0];
    const int*   labels = (const int*)d_in[1];
    const int*   mh     = (const int*)d_in[2];
    const int*   mr     = (const int*)d_in[3];
    const int*   mt     = (const int*)d_in[4];
    const float* E      = (const float*)d_in[5];
    const float* Rel    = (const float*)d_in[6];
    const float* wih    = (const float*)d_in[7];
    const float* whh    = (const float*)d_in[8];
    const float* bih    = (const float*)d_in[9];
    const float* bhh    = (const float*)d_in[10];
    float* out = (float*)d_out;
    float* ws  = (float*)d_ws;

    // workspace layout (floats)
    float* GI0     = ws;                 // 512*192 = 98304
    float* GI1     = GI0 + 98304;        // 98304
    float* ys0     = GI1 + 98304;        // 32768
    float* ys1     = ys0 + 32768;        // 32768
    float* hfin    = ys1 + 32768;        // 64
    float* o0      = hfin + 64;          // 32768
    float* osum    = o0 + 32768;         // 32768
    float* relnorm = osum + 32768;       // 32
    float* kge_p   = relnorm + 32;       // 1024
    float* l2_p    = kge_p + 1024;       // 512

    // gi0: GI for hop 0 (x = entity_emb[items]) + per-relation sqnorms
    gi_kernel<<<NB + NRELS, 64, 0, stream>>>(E, items, wih, bih, Rel, GI0, relnorm);
    // att0: attention hop0 + KGE both hops + L2 partials (no GRU dependency)
    att0<<<NB, 256, 0, stream>>>(E, Rel, items, mh, mr, mt, relnorm, o0, kge_p, l2_p);
    // gru0: hop-0 recurrence (4-wave k-split, ys in LDS)
    gru_kernel<<<1, 256, 0, stream>>>(GI0, whh, bhh, nullptr, ys0, hfin);
    // gi1: GI for hop 1 (x = ys0)
    gi_kernel<<<NB, 64, 0, stream>>>(ys0, nullptr, wih, bih, Rel, GI1, relnorm);
    // att1: attention hop1 + o_sum (needs ys0 only)
    att1<<<NB, 256, 0, stream>>>(E, Rel, mh, mr, mt, ys0, o0, osum);
    // gru1: hop-1 recurrence
    gru_kernel<<<1, 256, 0, stream>>>(GI1, whh, bhh, hfin, ys1, nullptr);
    // finalize: scores + losses
    finalize<<<1, 512, 0, stream>>>(ys1, osum, labels, kge_p, l2_p, out);
}

// Round 7
// 665.731 us; speedup vs baseline: 1.1157x; 1.1157x over previous
//
#include <hip/hip_runtime.h>

#define DIM   64
#define G3    192      // 3*DIM
#define NB    512      // BATCH
#define NM    32       // N_MEM
#define NRELS 32
#define KGE_W 0.01f
#define L2_W  1e-7f
#define EPSC  1e-7f

// ---------- helpers ----------

__device__ inline float bcast(float v, int srclane) {
    return __int_as_float(__builtin_amdgcn_readlane(__float_as_int(v), srclane));
}

__device__ inline float sigmoidf_(float x) { return 1.0f / (1.0f + __expf(-x)); }
__device__ inline float tanhf_(float x)    { return 1.0f - 2.0f / (1.0f + __expf(2.0f * x)); }

__device__ inline float wave_sum(float v) {
#pragma unroll
    for (int off = 32; off > 0; off >>= 1) v += __shfl_xor(v, off, 64);
    return v;
}
__device__ inline float wave_max(float v) {
#pragma unroll
    for (int off = 32; off > 0; off >>= 1) v = fmaxf(v, __shfl_xor(v, off, 64));
    return v;
}

// ---------- X-macros for 192 named scalar weights ----------

#define FOR64(F) F(0)F(1)F(2)F(3)F(4)F(5)F(6)F(7)F(8)F(9)F(10)F(11)F(12)F(13)F(14)F(15) \
                 F(16)F(17)F(18)F(19)F(20)F(21)F(22)F(23)F(24)F(25)F(26)F(27)F(28)F(29)F(30)F(31) \
                 F(32)F(33)F(34)F(35)F(36)F(37)F(38)F(39)F(40)F(41)F(42)F(43)F(44)F(45)F(46)F(47) \
                 F(48)F(49)F(50)F(51)F(52)F(53)F(54)F(55)F(56)F(57)F(58)F(59)F(60)F(61)F(62)F(63)

#define FOR32_0(F) F(0)F(1)F(2)F(3)F(4)F(5)F(6)F(7)F(8)F(9)F(10)F(11)F(12)F(13)F(14)F(15) \
                   F(16)F(17)F(18)F(19)F(20)F(21)F(22)F(23)F(24)F(25)F(26)F(27)F(28)F(29)F(30)F(31)
#define FOR32_1(F) F(32)F(33)F(34)F(35)F(36)F(37)F(38)F(39)F(40)F(41)F(42)F(43)F(44)F(45)F(46)F(47) \
                   F(48)F(49)F(50)F(51)F(52)F(53)F(54)F(55)F(56)F(57)F(58)F(59)F(60)F(61)F(62)F(63)

// ---------- GRU scan: ONE wave, weights in regs, h broadcast via LDS ----------
// Lane i owns output rows {i, 64+i, 128+i}. State h is distributed (lane k
// holds h_k). Per step: h is written once to LDS (ds_write), then read back
// as 64 wave-uniform ds_read broadcasts with constant offsets — these issue
// on the LDS pipe in the idle slots between VALU FMAs (a wave64 VALU op
// occupies the SIMD 2 cycles but the issue port only 1). No readlanes, no
// barriers, no cross-wave traffic. Single-buffered LDS is safe: the step-t+1
// write's data transitively depends on every step-t read's result.

__device__ __forceinline__ void gru_scan(const float* __restrict__ GI,   // [NB][192]
                                         const float* __restrict__ whh,  // [192][64]
                                         const float* __restrict__ bhh,  // [192]
                                         const float* __restrict__ h0,   // [64] or nullptr
                                         float* __restrict__ ys,         // [NB][64]
                                         float* __restrict__ hfin_out)   // [64] or nullptr
{
    __shared__ float hbuf[DIM];
    const int lane = threadIdx.x & 63;

    const float* wrp = whh + (0 * DIM + lane) * DIM;
    const float* wzp = whh + (1 * DIM + lane) * DIM;
    const float* wnp = whh + (2 * DIM + lane) * DIM;

#define DW(i) float wr##i, wz##i, wn##i;
    FOR64(DW)
#undef DW
#define LW(i) wr##i = wrp[i]; wz##i = wzp[i]; wn##i = wnp[i];
    FOR64(LW)
#undef LW

    const float br = bhh[lane], bz = bhh[DIM + lane], bn = bhh[2 * DIM + lane];

    float h = h0 ? h0[lane] : 0.0f;

    // GI register pipeline, distance 2
    float c0 = GI[0*G3 + lane], c1 = GI[0*G3 + DIM + lane], c2 = GI[0*G3 + 2*DIM + lane];
    float d0 = GI[1*G3 + lane], d1 = GI[1*G3 + DIM + lane], d2 = GI[1*G3 + 2*DIM + lane];

    for (int t = 0; t < NB; ++t) {
        hbuf[lane] = h;   // ds_write; consumed below by wave-uniform reads

        const int tp = (t + 2 < NB) ? t + 2 : NB - 1;
        const float* gp = GI + tp * G3;
        float p0 = gp[lane], p1 = gp[DIM + lane], p2 = gp[2 * DIM + lane];

        float ar0 = 0.f, az0 = 0.f, an0 = 0.f;
        float ar1 = 0.f, az1 = 0.f, an1 = 0.f;

#define S0(i) { float hk = hbuf[i]; ar0 = fmaf(wr##i, hk, ar0); az0 = fmaf(wz##i, hk, az0); an0 = fmaf(wn##i, hk, an0); }
        FOR32_0(S0)
#undef S0
#define S1(i) { float hk = hbuf[i]; ar1 = fmaf(wr##i, hk, ar1); az1 = fmaf(wz##i, hk, az1); an1 = fmaf(wn##i, hk, an1); }
        FOR32_1(S1)
#undef S1

        float ghr = (ar0 + ar1) + br;
        float ghz = (az0 + az1) + bz;
        float ghn = (an0 + an1) + bn;

        float r = sigmoidf_(c0 + ghr);
        float z = sigmoidf_(c1 + ghz);
        float n = tanhf_(c2 + r * ghn);
        h = n + z * (h - n);               // (1-z)*n + z*h

        ys[t * DIM + lane] = h;
        c0 = d0; c1 = d1; c2 = d2;
        d0 = p0; d1 = p1; d2 = p2;
    }
    if (hfin_out) hfin_out[lane] = h;
}

// ---------- gi: GI = wih @ x + bih (+ per-relation sqnorm on extra blocks) ----------

__global__ __launch_bounds__(64) void gi_kernel(const float* __restrict__ xsrc,
                                                const int* __restrict__ idx,    // nullptr => direct
                                                const float* __restrict__ wih,  // [192][64]
                                                const float* __restrict__ bih,  // [192]
                                                const float* __restrict__ Rel,  // [32][4096]
                                                float* __restrict__ GI,         // [NB][192]
                                                float* __restrict__ relnorm)    // [32]
{
    const int blk = blockIdx.x, lane = threadIdx.x;
    if (blk >= NB) {
        const int r = blk - NB;
        const float* R = Rel + r * DIM * DIM;
        float a = 0.0f;
#pragma unroll 4
        for (int i = 0; i < DIM; ++i) { float v = R[i * DIM + lane]; a = fmaf(v, v, a); }
        a = wave_sum(a);
        if (lane == 0) relnorm[r] = a;
        return;
    }
    const int b = blk;
    float xv = idx ? xsrc[idx[b] * DIM + lane] : xsrc[b * DIM + lane];
    float a0 = bih[lane], a1 = bih[DIM + lane], a2 = bih[2 * DIM + lane];
    const float* w0 = wih + (0 * DIM + lane) * DIM;
    const float* w1 = wih + (1 * DIM + lane) * DIM;
    const float* w2 = wih + (2 * DIM + lane) * DIM;
#pragma unroll 4
    for (int k = 0; k < DIM; ++k) {
        float xk = bcast(xv, k);
        a0 = fmaf(w0[k], xk, a0);
        a1 = fmaf(w1[k], xk, a1);
        a2 = fmaf(w2[k], xk, a2);
    }
    float* gp = GI + b * G3;
    gp[lane] = a0; gp[DIM + lane] = a1; gp[2 * DIM + lane] = a2;
}

// ---------- fused0: block 0 = GRU hop0; blocks 1..512 = att hop0 + KGE + L2 ----------

__global__ __launch_bounds__(256, 1) void fused0(const float* __restrict__ E,
                                              const float* __restrict__ Rel,
                                              const int* __restrict__ items,
                                              const int* __restrict__ mh,
                                              const int* __restrict__ mr,
                                              const int* __restrict__ mt,
                                              const float* __restrict__ GI,
                                              const float* __restrict__ whh,
                                              const float* __restrict__ bhh,
                                              const float* __restrict__ relnorm,
                                              float* __restrict__ ys0,
                                              float* __restrict__ hfin,
                                              float* __restrict__ o0,
                                              float* __restrict__ kge_part,   // [NB][2]
                                              float* __restrict__ l2_part)    // [NB]
{
    if (blockIdx.x == 0) {
        if (threadIdx.x < 64) gru_scan(GI, whh, bhh, nullptr, ys0, hfin);
        return;
    }

    const int b = blockIdx.x - 1;
    const int tid = threadIdx.x, lane = tid & 63, wave = tid >> 6;
    __shared__ float logits[NM], probs[NM], opart[4][DIM], wred[4][4];

    float iv = E[items[b] * DIM + lane];
    float kge0 = 0.0f, kge1 = 0.0f, l2acc = 0.0f, r2acc = 0.0f;

    for (int mm = 0; mm < 8; ++mm) {
        const int m = wave * 8 + mm;
        const int base = b * NM + m;                 // hop 0
        const int hidx = mh[base], ridx = mr[base], tidx = mt[base];
        float hv = E[hidx * DIM + lane];
        float tv = E[tidx * DIM + lane];
        l2acc = fmaf(hv, hv, l2acc);
        l2acc = fmaf(tv, tv, l2acc);
        r2acc += relnorm[ridx];
        const float* R = Rel + ridx * DIM * DIM;
        float accA = 0.0f, accK = 0.0f;
#pragma unroll 4
        for (int i = 0; i < DIM; ++i) {
            float rv = R[i * DIM + lane];
            accA = fmaf(bcast(iv, i), rv, accA);
            accK = fmaf(bcast(hv, i), rv, accK);
        }
        float la = wave_sum(accA * hv);              // item^T R h
        float lk = wave_sum(accK * tv);              // h^T R t
        if (lane == 0) logits[m] = la;
        kge0 += sigmoidf_(lk);
    }
    for (int mm = 0; mm < 8; ++mm) {
        const int m = wave * 8 + mm;
        const int base = NB * NM + b * NM + m;       // hop 1
        const int hidx = mh[base], ridx = mr[base], tidx = mt[base];
        float hv = E[hidx * DIM + lane];
        float tv = E[tidx * DIM + lane];
        l2acc = fmaf(hv, hv, l2acc);
        l2acc = fmaf(tv, tv, l2acc);
        r2acc += relnorm[ridx];
        const float* R = Rel + ridx * DIM * DIM;
        float accK = 0.0f;
#pragma unroll 4
        for (int i = 0; i < DIM; ++i)
            accK = fmaf(bcast(hv, i), R[i * DIM + lane], accK);
        kge1 += sigmoidf_(wave_sum(accK * tv));
    }
    __syncthreads();

    if (wave == 0) {
        float v = (lane < NM) ? logits[lane] : -1e30f;
        float mx = wave_max(v);
        float e = (lane < NM) ? __expf(v - mx) : 0.0f;
        float ssum = wave_sum(e);
        if (lane < NM) probs[lane] = e / ssum;
    }
    __syncthreads();

    float od = 0.0f;
    for (int mm = 0; mm < 8; ++mm) {
        const int m = wave * 8 + mm;
        const int tidx = mt[b * NM + m];
        od = fmaf(probs[m], E[tidx * DIM + lane], od);
    }
    opart[wave][lane] = od;
    float l2tot = wave_sum(l2acc);
    if (lane == 0) { wred[wave][0] = kge0; wred[wave][1] = kge1; wred[wave][2] = l2tot + r2acc; }
    __syncthreads();
    if (wave == 0)
        o0[b * DIM + lane] = opart[0][lane] + opart[1][lane] + opart[2][lane] + opart[3][lane];
    if (tid == 0) {
        kge_part[b * 2 + 0] = wred[0][0] + wred[1][0] + wred[2][0] + wred[3][0];
        kge_part[b * 2 + 1] = wred[0][1] + wred[1][1] + wred[2][1] + wred[3][1];
        l2_part[b]          = wred[0][2] + wred[1][2] + wred[2][2] + wred[3][2];
    }
}

// ---------- fused1: block 0 = GRU hop1; blocks 1..512 = att hop1 + o_sum ----------

__global__ __launch_bounds__(256, 1) void fused1(const float* __restrict__ E,
                                              const float* __restrict__ Rel,
                                              const int* __restrict__ mh,
                                              const int* __restrict__ mr,
                                              const int* __restrict__ mt,
                                              const float* __restrict__ GI,
                                              const float* __restrict__ whh,
                                              const float* __restrict__ bhh,
                                              const float* __restrict__ hfin,
                                              const float* __restrict__ ys0,
                                              float* __restrict__ ys1,
                                              const float* __restrict__ o0,
                                              float* __restrict__ osum)
{
    if (blockIdx.x == 0) {
        if (threadIdx.x < 64) gru_scan(GI, whh, bhh, hfin, ys1, nullptr);
        return;
    }

    const int b = blockIdx.x - 1;
    const int tid = threadIdx.x, lane = tid & 63, wave = tid >> 6;
    __shared__ float logits[NM], probs[NM], opart[4][DIM];

    float iv = ys0[b * DIM + lane];   // item_emb after 1 GRU pass

    for (int mm = 0; mm < 8; ++mm) {
        const int m = wave * 8 + mm;
        const int base = NB * NM + b * NM + m;       // hop 1
        const int hidx = mh[base], ridx = mr[base];
        float hv = E[hidx * DIM + lane];
        const float* R = Rel + ridx * DIM * DIM;
        float accA = 0.0f;
#pragma unroll 4
        for (int i = 0; i < DIM; ++i)
            accA = fmaf(bcast(iv, i), R[i * DIM + lane], accA);
        float la = wave_sum(accA * hv);
        if (lane == 0) logits[m] = la;
    }
    __syncthreads();
    if (wave == 0) {
        float v = (lane < NM) ? logits[lane] : -1e30f;
        float mx = wave_max(v);
        float e = (lane < NM) ? __expf(v - mx) : 0.0f;
        float ssum = wave_sum(e);
        if (lane < NM) probs[lane] = e / ssum;
    }
    __syncthreads();
    float od = 0.0f;
    for (int mm = 0; mm < 8; ++mm) {
        const int m = wave * 8 + mm;
        const int tidx = mt[NB * NM + b * NM + m];
        od = fmaf(probs[m], E[tidx * DIM + lane], od);
    }
    opart[wave][lane] = od;
    __syncthreads();
    if (wave == 0)
        osum[b * DIM + lane] = o0[b * DIM + lane] +
            opart[0][lane] + opart[1][lane] + opart[2][lane] + opart[3][lane];
}

// ---------- finalize: scores + losses ----------

__global__ __launch_bounds__(512) void finalize(const float* __restrict__ ys1,
                                                const float* __restrict__ osum,
                                                const int* __restrict__ labels,
                                                const float* __restrict__ kge_part,
                                                const float* __restrict__ l2_part,
                                                float* __restrict__ out)
{
    __shared__ float red[512];
    const int tid = threadIdx.x;

    float dot = 0.0f;
    const float* a = ys1 + tid * DIM;
    const float* c = osum + tid * DIM;
#pragma unroll 8
    for (int k = 0; k < DIM; ++k) dot = fmaf(a[k], c[k], dot);
    float score = sigmoidf_(dot);
    out[tid] = score;

    float s = fminf(fmaxf(score, EPSC), 1.0f - EPSC);
    float term = labels[tid] ? logf(s) : log1pf(-s);

    float bsum, ksum, lsum;
    {
        red[tid] = term; __syncthreads();
#pragma unroll
        for (int st = 256; st > 0; st >>= 1) { if (tid < st) red[tid] += red[tid + st]; __syncthreads(); }
        bsum = red[0]; __syncthreads();
    }
    {
        red[tid] = kge_part[2 * tid] + kge_part[2 * tid + 1]; __syncthreads();
#pragma unroll
        for (int st = 256; st > 0; st >>= 1) { if (tid < st) red[tid] += red[tid + st]; __syncthreads(); }
        ksum = red[0]; __syncthreads();
    }
    {
        red[tid] = l2_part[tid]; __syncthreads();
#pragma unroll
        for (int st = 256; st > 0; st >>= 1) { if (tid < st) red[tid] += red[tid + st]; __syncthreads(); }
        lsum = red[0];
    }

    if (tid == 0) {
        float base = -bsum / (float)NB;
        float kge  = -KGE_W * ksum / (float)(NB * NM);
        float l2   = L2_W * lsum;
        out[NB + 0] = base;
        out[NB + 1] = kge;
        out[NB + 2] = l2;
        out[NB + 3] = base + kge + l2;
    }
}

// ---------- host ----------

extern "C" void kernel_launch(void* const* d_in, const int* in_sizes, int n_in,
                              void* d_out, int out_size, void* d_ws, size_t ws_size,
                              hipStream_t stream) {
    const int*   items  = (const int*)d_in[0];
    const int*   labels = (const int*)d_in[1];
    const int*   mh     = (const int*)d_in[2];
    const int*   mr     = (const int*)d_in[3];
    const int*   mt     = (const int*)d_in[4];
    const float* E      = (const float*)d_in[5];
    const float* Rel    = (const float*)d_in[6];
    const float* wih    = (const float*)d_in[7];
    const float* whh    = (const float*)d_in[8];
    const float* bih    = (const float*)d_in[9];
    const float* bhh    = (const float*)d_in[10];
    float* out = (float*)d_out;
    float* ws  = (float*)d_ws;

    // workspace layout (floats)
    float* GI0     = ws;                 // 512*192 = 98304
    float* GI1     = GI0 + 98304;        // 98304
    float* ys0     = GI1 + 98304;        // 32768
    float* ys1     = ys0 + 32768;        // 32768
    float* hfin    = ys1 + 32768;        // 64
    float* o0      = hfin + 64;          // 32768
    float* osum    = o0 + 32768;         // 32768
    float* relnorm = osum + 32768;       // 32
    float* kge_p   = relnorm + 32;       // 1024
    float* l2_p    = kge_p + 1024;       // 512

    // gi0: GI for hop 0 (x = entity_emb[items]) + per-relation sqnorms
    gi_kernel<<<NB + NRELS, 64, 0, stream>>>(E, items, wih, bih, Rel, GI0, relnorm);
    // fused0: GRU hop0 (block 0) || attention hop0 + KGE both hops + L2
    fused0<<<NB + 1, 256, 0, stream>>>(E, Rel, items, mh, mr, mt, GI0, whh, bhh,
                                       relnorm, ys0, hfin, o0, kge_p, l2_p);
    // gi1: GI for hop 1 (x = ys0)
    gi_kernel<<<NB, 64, 0, stream>>>(ys0, nullptr, wih, bih, Rel, GI1, relnorm);
    // fused1: GRU hop1 (block 0) || attention hop1 + o_sum
    fused1<<<NB + 1, 256, 0, stream>>>(E, Rel, mh, mr, mt, GI1, whh, bhh, hfin,
                                       ys0, ys1, o0, osum);
    // finalize: scores + losses
    finalize<<<1, 512, 0, stream>>>(ys1, osum, labels, kge_p, l2_p, out);
}

// Round 8
// 547.941 us; speedup vs baseline: 1.3556x; 1.2150x over previous
//
#include <hip/hip_runtime.h>

#define DIM   64
#define G3    192      // 3*DIM
#define NB    512      // BATCH
#define NM    32       // N_MEM
#define NRELS 32
#define KGE_W 0.01f
#define L2_W  1e-7f
#define EPSC  1e-7f

// ---------- helpers ----------

typedef _Float16 h2 __attribute__((ext_vector_type(2)));

__device__ __forceinline__ float fdot2_(h2 a, h2 b, float c) {
#if __has_builtin(__builtin_amdgcn_fdot2)
    return __builtin_amdgcn_fdot2(a, b, c, false);   // v_dot2_f32_f16
#else
    return fmaf((float)a.x, (float)b.x, fmaf((float)a.y, (float)b.y, c));
#endif
}

__device__ inline float bcast(float v, int srclane) {
    return __int_as_float(__builtin_amdgcn_readlane(__float_as_int(v), srclane));
}

__device__ inline float sigmoidf_(float x) { return 1.0f / (1.0f + __expf(-x)); }
__device__ inline float tanhf_(float x)    { return 1.0f - 2.0f / (1.0f + __expf(2.0f * x)); }

__device__ inline float wave_sum(float v) {
#pragma unroll
    for (int off = 32; off > 0; off >>= 1) v += __shfl_xor(v, off, 64);
    return v;
}
__device__ inline float wave_max(float v) {
#pragma unroll
    for (int off = 32; off > 0; off >>= 1) v = fmaxf(v, __shfl_xor(v, off, 64));
    return v;
}

// ---------- X-macro over 32 k-pairs ----------

#define FOR32(F) F(0)F(1)F(2)F(3)F(4)F(5)F(6)F(7)F(8)F(9)F(10)F(11)F(12)F(13)F(14)F(15) \
                 F(16)F(17)F(18)F(19)F(20)F(21)F(22)F(23)F(24)F(25)F(26)F(27)F(28)F(29)F(30)F(31)

// ---------- GRU scan: ONE wave, f16 weights in 96 named VGPRs, dot2 matvec ----------
// Lane i owns output rows {i, 64+i, 128+i}. State h stays f32, distributed
// (lane k holds h_k). Per step: h -> f16, packed into pairs via 2 bpermutes,
// broadcast as 32 uniform readlanes of f16x2; each gate row = 32 v_dot2_f32_f16
// (f32 accumulate). No LDS, no barriers, no AGPR round-trips.

__device__ __forceinline__ void gru_scan(const float* __restrict__ GI,   // [NB][192]
                                         const float* __restrict__ whh,  // [192][64]
                                         const float* __restrict__ bhh,  // [192]
                                         const float* __restrict__ h0,   // [64] or nullptr
                                         float* __restrict__ ys,         // [NB][64]
                                         float* __restrict__ hfin_out)   // [64] or nullptr
{
    const int lane = threadIdx.x & 63;

    const float* wrp = whh + (0 * DIM + lane) * DIM;
    const float* wzp = whh + (1 * DIM + lane) * DIM;
    const float* wnp = whh + (2 * DIM + lane) * DIM;

#define DW(j) h2 wr##j, wz##j, wn##j;
    FOR32(DW)
#undef DW
#define LW(j) wr##j = (h2){(_Float16)wrp[2*(j)], (_Float16)wrp[2*(j)+1]}; \
              wz##j = (h2){(_Float16)wzp[2*(j)], (_Float16)wzp[2*(j)+1]}; \
              wn##j = (h2){(_Float16)wnp[2*(j)], (_Float16)wnp[2*(j)+1]};
    FOR32(LW)
#undef LW

    const float br = bhh[lane], bz = bhh[DIM + lane], bn = bhh[2 * DIM + lane];

    float h = h0 ? h0[lane] : 0.0f;

    // GI register pipeline, distance 2
    float c0 = GI[0*G3 + lane], c1 = GI[0*G3 + DIM + lane], c2 = GI[0*G3 + 2*DIM + lane];
    float d0 = GI[1*G3 + lane], d1 = GI[1*G3 + DIM + lane], d2 = GI[1*G3 + 2*DIM + lane];

    for (int t = 0; t < NB; ++t) {
        // pack h into f16 pairs: lane j (j<32) holds (h_2j, h_2j+1)
        unsigned short hu = __builtin_bit_cast(unsigned short, (_Float16)h);
        int lo = __shfl((int)(unsigned)hu, (2 * lane) & 63);
        int hi = __shfl((int)(unsigned)hu, (2 * lane + 1) & 63);
        unsigned packed = ((unsigned)lo & 0xffffu) | ((unsigned)hi << 16);

        const int tp = (t + 2 < NB) ? t + 2 : NB - 1;
        const float* gp = GI + tp * G3;
        float p0 = gp[lane], p1 = gp[DIM + lane], p2 = gp[2 * DIM + lane];

        float ar = 0.f, az = 0.f, an = 0.f;
#define SJ(j) { h2 hb = __builtin_bit_cast(h2, (unsigned)__builtin_amdgcn_readlane((int)packed, j)); \
                ar = fdot2_(wr##j, hb, ar); az = fdot2_(wz##j, hb, az); an = fdot2_(wn##j, hb, an); }
        FOR32(SJ)
#undef SJ

        float ghr = ar + br;
        float ghz = az + bz;
        float ghn = an + bn;

        float r = sigmoidf_(c0 + ghr);
        float z = sigmoidf_(c1 + ghz);
        float n = tanhf_(c2 + r * ghn);
        h = n + z * (h - n);               // (1-z)*n + z*h

        ys[t * DIM + lane] = h;
        c0 = d0; c1 = d1; c2 = d2;
        d0 = p0; d1 = p1; d2 = p2;
    }
    if (hfin_out) hfin_out[lane] = h;
}

// ---------- gi: GI = wih @ x + bih (+ per-relation sqnorm on extra blocks) ----------

__global__ __launch_bounds__(64) void gi_kernel(const float* __restrict__ xsrc,
                                                const int* __restrict__ idx,    // nullptr => direct
                                                const float* __restrict__ wih,  // [192][64]
                                                const float* __restrict__ bih,  // [192]
                                                const float* __restrict__ Rel,  // [32][4096]
                                                float* __restrict__ GI,         // [NB][192]
                                                float* __restrict__ relnorm)    // [32]
{
    const int blk = blockIdx.x, lane = threadIdx.x;
    if (blk >= NB) {
        const int r = blk - NB;
        const float* R = Rel + r * DIM * DIM;
        float a = 0.0f;
#pragma unroll 4
        for (int i = 0; i < DIM; ++i) { float v = R[i * DIM + lane]; a = fmaf(v, v, a); }
        a = wave_sum(a);
        if (lane == 0) relnorm[r] = a;
        return;
    }
    const int b = blk;
    float xv = idx ? xsrc[idx[b] * DIM + lane] : xsrc[b * DIM + lane];
    float a0 = bih[lane], a1 = bih[DIM + lane], a2 = bih[2 * DIM + lane];
    const float* w0 = wih + (0 * DIM + lane) * DIM;
    const float* w1 = wih + (1 * DIM + lane) * DIM;
    const float* w2 = wih + (2 * DIM + lane) * DIM;
#pragma unroll 4
    for (int k = 0; k < DIM; ++k) {
        float xk = bcast(xv, k);
        a0 = fmaf(w0[k], xk, a0);
        a1 = fmaf(w1[k], xk, a1);
        a2 = fmaf(w2[k], xk, a2);
    }
    float* gp = GI + b * G3;
    gp[lane] = a0; gp[DIM + lane] = a1; gp[2 * DIM + lane] = a2;
}

// ---------- fused0: block 0 = GRU hop0; blocks 1..512 = att hop0 + KGE + L2 ----------

__global__ __launch_bounds__(256, 1) void fused0(const float* __restrict__ E,
                                              const float* __restrict__ Rel,
                                              const int* __restrict__ items,
                                              const int* __restrict__ mh,
                                              const int* __restrict__ mr,
                                              const int* __restrict__ mt,
                                              const float* __restrict__ GI,
                                              const float* __restrict__ whh,
                                              const float* __restrict__ bhh,
                                              const float* __restrict__ relnorm,
                                              float* __restrict__ ys0,
                                              float* __restrict__ hfin,
                                              float* __restrict__ o0,
                                              float* __restrict__ kge_part,   // [NB][2]
                                              float* __restrict__ l2_part)    // [NB]
{
    if (blockIdx.x == 0) {
        if (threadIdx.x < 64) gru_scan(GI, whh, bhh, nullptr, ys0, hfin);
        return;
    }

    const int b = blockIdx.x - 1;
    const int tid = threadIdx.x, lane = tid & 63, wave = tid >> 6;
    __shared__ float logits[NM], probs[NM], opart[4][DIM], wred[4][4];

    float iv = E[items[b] * DIM + lane];
    float kge0 = 0.0f, kge1 = 0.0f, l2acc = 0.0f, r2acc = 0.0f;

    for (int mm = 0; mm < 8; ++mm) {
        const int m = wave * 8 + mm;
        const int base = b * NM + m;                 // hop 0
        const int hidx = mh[base], ridx = mr[base], tidx = mt[base];
        float hv = E[hidx * DIM + lane];
        float tv = E[tidx * DIM + lane];
        l2acc = fmaf(hv, hv, l2acc);
        l2acc = fmaf(tv, tv, l2acc);
        r2acc += relnorm[ridx];
        const float* R = Rel + ridx * DIM * DIM;
        float accA = 0.0f, accK = 0.0f;
#pragma unroll 4
        for (int i = 0; i < DIM; ++i) {
            float rv = R[i * DIM + lane];
            accA = fmaf(bcast(iv, i), rv, accA);
            accK = fmaf(bcast(hv, i), rv, accK);
        }
        float la = wave_sum(accA * hv);              // item^T R h
        float lk = wave_sum(accK * tv);              // h^T R t
        if (lane == 0) logits[m] = la;
        kge0 += sigmoidf_(lk);
    }
    for (int mm = 0; mm < 8; ++mm) {
        const int m = wave * 8 + mm;
        const int base = NB * NM + b * NM + m;       // hop 1
        const int hidx = mh[base], ridx = mr[base], tidx = mt[base];
        float hv = E[hidx * DIM + lane];
        float tv = E[tidx * DIM + lane];
        l2acc = fmaf(hv, hv, l2acc);
        l2acc = fmaf(tv, tv, l2acc);
        r2acc += relnorm[ridx];
        const float* R = Rel + ridx * DIM * DIM;
        float accK = 0.0f;
#pragma unroll 4
        for (int i = 0; i < DIM; ++i)
            accK = fmaf(bcast(hv, i), R[i * DIM + lane], accK);
        kge1 += sigmoidf_(wave_sum(accK * tv));
    }
    __syncthreads();

    if (wave == 0) {
        float v = (lane < NM) ? logits[lane] : -1e30f;
        float mx = wave_max(v);
        float e = (lane < NM) ? __expf(v - mx) : 0.0f;
        float ssum = wave_sum(e);
        if (lane < NM) probs[lane] = e / ssum;
    }
    __syncthreads();

    float od = 0.0f;
    for (int mm = 0; mm < 8; ++mm) {
        const int m = wave * 8 + mm;
        const int tidx = mt[b * NM + m];
        od = fmaf(probs[m], E[tidx * DIM + lane], od);
    }
    opart[wave][lane] = od;
    float l2tot = wave_sum(l2acc);
    if (lane == 0) { wred[wave][0] = kge0; wred[wave][1] = kge1; wred[wave][2] = l2tot + r2acc; }
    __syncthreads();
    if (wave == 0)
        o0[b * DIM + lane] = opart[0][lane] + opart[1][lane] + opart[2][lane] + opart[3][lane];
    if (tid == 0) {
        kge_part[b * 2 + 0] = wred[0][0] + wred[1][0] + wred[2][0] + wred[3][0];
        kge_part[b * 2 + 1] = wred[0][1] + wred[1][1] + wred[2][1] + wred[3][1];
        l2_part[b]          = wred[0][2] + wred[1][2] + wred[2][2] + wred[3][2];
    }
}

// ---------- fused1: block 0 = GRU hop1; blocks 1..512 = att hop1 + o_sum ----------

__global__ __launch_bounds__(256, 1) void fused1(const float* __restrict__ E,
                                              const float* __restrict__ Rel,
                                              const int* __restrict__ mh,
                                              const int* __restrict__ mr,
                                              const int* __restrict__ mt,
                                              const float* __restrict__ GI,
                                              const float* __restrict__ whh,
                                              const float* __restrict__ bhh,
                                              const float* __restrict__ hfin,
                                              const float* __restrict__ ys0,
                                              float* __restrict__ ys1,
                                              const float* __restrict__ o0,
                                              float* __restrict__ osum)
{
    if (blockIdx.x == 0) {
        if (threadIdx.x < 64) gru_scan(GI, whh, bhh, hfin, ys1, nullptr);
        return;
    }

    const int b = blockIdx.x - 1;
    const int tid = threadIdx.x, lane = tid & 63, wave = tid >> 6;
    __shared__ float logits[NM], probs[NM], opart[4][DIM];

    float iv = ys0[b * DIM + lane];   // item_emb after 1 GRU pass

    for (int mm = 0; mm < 8; ++mm) {
        const int m = wave * 8 + mm;
        const int base = NB * NM + b * NM + m;       // hop 1
        const int hidx = mh[base], ridx = mr[base];
        float hv = E[hidx * DIM + lane];
        const float* R = Rel + ridx * DIM * DIM;
        float accA = 0.0f;
#pragma unroll 4
        for (int i = 0; i < DIM; ++i)
            accA = fmaf(bcast(iv, i), R[i * DIM + lane], accA);
        float la = wave_sum(accA * hv);
        if (lane == 0) logits[m] = la;
    }
    __syncthreads();
    if (wave == 0) {
        float v = (lane < NM) ? logits[lane] : -1e30f;
        float mx = wave_max(v);
        float e = (lane < NM) ? __expf(v - mx) : 0.0f;
        float ssum = wave_sum(e);
        if (lane < NM) probs[lane] = e / ssum;
    }
    __syncthreads();
    float od = 0.0f;
    for (int mm = 0; mm < 8; ++mm) {
        const int m = wave * 8 + mm;
        const int tidx = mt[NB * NM + b * NM + m];
        od = fmaf(probs[m], E[tidx * DIM + lane], od);
    }
    opart[wave][lane] = od;
    __syncthreads();
    if (wave == 0)
        osum[b * DIM + lane] = o0[b * DIM + lane] +
            opart[0][lane] + opart[1][lane] + opart[2][lane] + opart[3][lane];
}

// ---------- finalize: scores + losses ----------

__global__ __launch_bounds__(512) void finalize(const float* __restrict__ ys1,
                                                const float* __restrict__ osum,
                                                const int* __restrict__ labels,
                                                const float* __restrict__ kge_part,
                                                const float* __restrict__ l2_part,
                                                float* __restrict__ out)
{
    __shared__ float red[512];
    const int tid = threadIdx.x;

    float dot = 0.0f;
    const float* a = ys1 + tid * DIM;
    const float* c = osum + tid * DIM;
#pragma unroll 8
    for (int k = 0; k < DIM; ++k) dot = fmaf(a[k], c[k], dot);
    float score = sigmoidf_(dot);
    out[tid] = score;

    float s = fminf(fmaxf(score, EPSC), 1.0f - EPSC);
    float term = labels[tid] ? logf(s) : log1pf(-s);

    float bsum, ksum, lsum;
    {
        red[tid] = term; __syncthreads();
#pragma unroll
        for (int st = 256; st > 0; st >>= 1) { if (tid < st) red[tid] += red[tid + st]; __syncthreads(); }
        bsum = red[0]; __syncthreads();
    }
    {
        red[tid] = kge_part[2 * tid] + kge_part[2 * tid + 1]; __syncthreads();
#pragma unroll
        for (int st = 256; st > 0; st >>= 1) { if (tid < st) red[tid] += red[tid + st]; __syncthreads(); }
        ksum = red[0]; __syncthreads();
    }
    {
        red[tid] = l2_part[tid]; __syncthreads();
#pragma unroll
        for (int st = 256; st > 0; st >>= 1) { if (tid < st) red[tid] += red[tid + st]; __syncthreads(); }
        lsum = red[0];
    }

    if (tid == 0) {
        float base = -bsum / (float)NB;
        float kge  = -KGE_W * ksum / (float)(NB * NM);
        float l2   = L2_W * lsum;
        out[NB + 0] = base;
        out[NB + 1] = kge;
        out[NB + 2] = l2;
        out[NB + 3] = base + kge + l2;
    }
}

// ---------- host ----------

extern "C" void kernel_launch(void* const* d_in, const int* in_sizes, int n_in,
                              void* d_out, int out_size, void* d_ws, size_t ws_size,
                              hipStream_t stream) {
    const int*   items  = (const int*)d_in[0];
    const int*   labels = (const int*)d_in[1];
    const int*   mh     = (const int*)d_in[2];
    const int*   mr     = (const int*)d_in[3];
    const int*   mt     = (const int*)d_in[4];
    const float* E      = (const float*)d_in[5];
    const float* Rel    = (const float*)d_in[6];
    const float* wih    = (const float*)d_in[7];
    const float* whh    = (const float*)d_in[8];
    const float* bih    = (const float*)d_in[9];
    const float* bhh    = (const float*)d_in[10];
    float* out = (float*)d_out;
    float* ws  = (float*)d_ws;

    // workspace layout (floats)
    float* GI0     = ws;                 // 512*192 = 98304
    float* GI1     = GI0 + 98304;        // 98304
    float* ys0     = GI1 + 98304;        // 32768
    float* ys1     = ys0 + 32768;        // 32768
    float* hfin    = ys1 + 32768;        // 64
    float* o0      = hfin + 64;          // 32768
    float* osum    = o0 + 32768;         // 32768
    float* relnorm = osum + 32768;       // 32
    float* kge_p   = relnorm + 32;       // 1024
    float* l2_p    = kge_p + 1024;       // 512

    // gi0: GI for hop 0 (x = entity_emb[items]) + per-relation sqnorms
    gi_kernel<<<NB + NRELS, 64, 0, stream>>>(E, items, wih, bih, Rel, GI0, relnorm);
    // fused0: GRU hop0 (block 0) || attention hop0 + KGE both hops + L2
    fused0<<<NB + 1, 256, 0, stream>>>(E, Rel, items, mh, mr, mt, GI0, whh, bhh,
                                       relnorm, ys0, hfin, o0, kge_p, l2_p);
    // gi1: GI for hop 1 (x = ys0)
    gi_kernel<<<NB, 64, 0, stream>>>(ys0, nullptr, wih, bih, Rel, GI1, relnorm);
    // fused1: GRU hop1 (block 0) || attention hop1 + o_sum
    fused1<<<NB + 1, 256, 0, stream>>>(E, Rel, mh, mr, mt, GI1, whh, bhh, hfin,
                                       ys0, ys1, o0, osum);
    // finalize: scores + losses
    finalize<<<1, 512, 0, stream>>>(ys1, osum, labels, kge_p, l2_p, out);
}

// Round 9
// 531.887 us; speedup vs baseline: 1.3965x; 1.0302x over previous
//
#include <hip/hip_runtime.h>

#define DIM   64
#define G3    192      // 3*DIM
#define NB    512      // BATCH
#define NM    32       // N_MEM
#define NRELS 32
#define CH    32       // GI chunk (steps) staged in LDS
#define NCH   (NB/CH)
#define KGE_W 0.01f
#define L2_W  1e-7f
#define EPSC  1e-7f

// ---------- helpers ----------

__device__ inline float bcast(float v, int srclane) {
    return __int_as_float(__builtin_amdgcn_readlane(__float_as_int(v), srclane));
}

__device__ inline float sigmoidf_(float x) { return 1.0f / (1.0f + __expf(-x)); }
__device__ inline float tanhf_(float x)    { return 1.0f - 2.0f / (1.0f + __expf(2.0f * x)); }

__device__ inline float wave_sum(float v) {
#pragma unroll
    for (int off = 32; off > 0; off >>= 1) v += __shfl_xor(v, off, 64);
    return v;
}
__device__ inline float wave_max(float v) {
#pragma unroll
    for (int off = 32; off > 0; off >>= 1) v = fmaxf(v, __shfl_xor(v, off, 64));
    return v;
}

// ---------- GRU with LDS-staged GI ----------
// Block 0 only. Wave 0 runs the serial recurrence reading GI from LDS
// (zero global loads in the loop). Waves 1-3 (192 threads) bulk-copy the
// next 32-step GI chunk global->LDS (float4), one chunk ahead, double
// buffered. One __syncthreads per chunk (16 per hop).

__device__ __forceinline__ void gru_scan_staged(float (*gibuf)[CH * G3],   // [2][CH*192] LDS
                                                const float* __restrict__ GI,   // [NB][192]
                                                const float* __restrict__ whh,  // [192][64]
                                                const float* __restrict__ bhh,  // [192]
                                                const float* __restrict__ h0,   // [64] or nullptr
                                                float* __restrict__ ys,         // [NB][64]
                                                float* __restrict__ hfin_out)   // [64] or nullptr
{
    const int tid  = threadIdx.x;
    const int lane = tid & 63;
    const int wave = tid >> 6;

    // prologue: stage chunk 0 into buffer 0
    if (wave != 0) {
        const int sid = tid - 64;                    // 0..191
        const float4* src = (const float4*)GI;
        float4* dst = (float4*)gibuf[0];
#pragma unroll
        for (int j = 0; j < 8; ++j) dst[sid + j * 192] = src[sid + j * 192];
    }
    __syncthreads();

    if (wave == 0) {
        // weights: rows {lane, 64+lane, 128+lane} (R3 form — proven baseline)
        float wr[DIM], wz[DIM], wn[DIM];
        {
            const float4* r4 = (const float4*)(whh + (0 * DIM + lane) * DIM);
            const float4* z4 = (const float4*)(whh + (1 * DIM + lane) * DIM);
            const float4* n4 = (const float4*)(whh + (2 * DIM + lane) * DIM);
#pragma unroll
            for (int i = 0; i < 16; ++i) {
                float4 a = r4[i]; wr[4*i] = a.x; wr[4*i+1] = a.y; wr[4*i+2] = a.z; wr[4*i+3] = a.w;
                float4 b = z4[i]; wz[4*i] = b.x; wz[4*i+1] = b.y; wz[4*i+2] = b.z; wz[4*i+3] = b.w;
                float4 c = n4[i]; wn[4*i] = c.x; wn[4*i+1] = c.y; wn[4*i+2] = c.z; wn[4*i+3] = c.w;
            }
        }
        const float br = bhh[lane], bz = bhh[DIM + lane], bn = bhh[2 * DIM + lane];
        float h = h0 ? h0[lane] : 0.0f;

        for (int c = 0; c < NCH; ++c) {
            const float* buf = gibuf[c & 1];
            for (int tl = 0; tl < CH; ++tl) {
                const float* gi = buf + tl * G3;
                float c0 = gi[lane], c1 = gi[DIM + lane], c2 = gi[2 * DIM + lane];  // ds_read

                float ar0 = 0.f, ar1 = 0.f, ar2 = 0.f, ar3 = 0.f;
                float az0 = 0.f, az1 = 0.f, az2 = 0.f, az3 = 0.f;
                float an0 = 0.f, an1 = 0.f, an2 = 0.f, an3 = 0.f;
#pragma unroll
                for (int k = 0; k < 16; ++k) {
                    float hk = bcast(h, k);
                    ar0 = fmaf(wr[k], hk, ar0); az0 = fmaf(wz[k], hk, az0); an0 = fmaf(wn[k], hk, an0);
                }
#pragma unroll
                for (int k = 16; k < 32; ++k) {
                    float hk = bcast(h, k);
                    ar1 = fmaf(wr[k], hk, ar1); az1 = fmaf(wz[k], hk, az1); an1 = fmaf(wn[k], hk, an1);
                }
#pragma unroll
                for (int k = 32; k < 48; ++k) {
                    float hk = bcast(h, k);
                    ar2 = fmaf(wr[k], hk, ar2); az2 = fmaf(wz[k], hk, az2); an2 = fmaf(wn[k], hk, an2);
                }
#pragma unroll
                for (int k = 48; k < 64; ++k) {
                    float hk = bcast(h, k);
                    ar3 = fmaf(wr[k], hk, ar3); az3 = fmaf(wz[k], hk, az3); an3 = fmaf(wn[k], hk, an3);
                }
                float ghr = ((ar0 + ar1) + (ar2 + ar3)) + br;
                float ghz = ((az0 + az1) + (az2 + az3)) + bz;
                float ghn = ((an0 + an1) + (an2 + an3)) + bn;

                float r = sigmoidf_(c0 + ghr);
                float z = sigmoidf_(c1 + ghz);
                float n = tanhf_(c2 + r * ghn);
                h = n + z * (h - n);               // (1-z)*n + z*h

                ys[(c * CH + tl) * DIM + lane] = h;
            }
            __syncthreads();                        // chunk boundary
        }
        if (hfin_out) hfin_out[lane] = h;
    } else {
        const int sid = tid - 64;                    // 0..191
        for (int c = 0; c < NCH; ++c) {
            if (c + 1 < NCH) {
                const float4* src = (const float4*)(GI + (size_t)(c + 1) * CH * G3);
                float4* dst = (float4*)gibuf[(c + 1) & 1];
#pragma unroll
                for (int j = 0; j < 8; ++j) dst[sid + j * 192] = src[sid + j * 192];
            }
            __syncthreads();
        }
    }
}

// ---------- gi: GI = wih @ x + bih (+ per-relation sqnorm on extra blocks) ----------

__global__ __launch_bounds__(64) void gi_kernel(const float* __restrict__ xsrc,
                                                const int* __restrict__ idx,    // nullptr => direct
                                                const float* __restrict__ wih,  // [192][64]
                                                const float* __restrict__ bih,  // [192]
                                                const float* __restrict__ Rel,  // [32][4096]
                                                float* __restrict__ GI,         // [NB][192]
                                                float* __restrict__ relnorm)    // [32]
{
    const int blk = blockIdx.x, lane = threadIdx.x;
    if (blk >= NB) {
        const int r = blk - NB;
        const float* R = Rel + r * DIM * DIM;
        float a = 0.0f;
#pragma unroll 4
        for (int i = 0; i < DIM; ++i) { float v = R[i * DIM + lane]; a = fmaf(v, v, a); }
        a = wave_sum(a);
        if (lane == 0) relnorm[r] = a;
        return;
    }
    const int b = blk;
    float xv = idx ? xsrc[idx[b] * DIM + lane] : xsrc[b * DIM + lane];
    float a0 = bih[lane], a1 = bih[DIM + lane], a2 = bih[2 * DIM + lane];
    const float* w0 = wih + (0 * DIM + lane) * DIM;
    const float* w1 = wih + (1 * DIM + lane) * DIM;
    const float* w2 = wih + (2 * DIM + lane) * DIM;
#pragma unroll 4
    for (int k = 0; k < DIM; ++k) {
        float xk = bcast(xv, k);
        a0 = fmaf(w0[k], xk, a0);
        a1 = fmaf(w1[k], xk, a1);
        a2 = fmaf(w2[k], xk, a2);
    }
    float* gp = GI + b * G3;
    gp[lane] = a0; gp[DIM + lane] = a1; gp[2 * DIM + lane] = a2;
}

// ---------- fused0: block 0 = GRU hop0 (staged); blocks 1..512 = att hop0 + KGE + L2 ----------

__global__ __launch_bounds__(256, 1) void fused0(const float* __restrict__ E,
                                              const float* __restrict__ Rel,
                                              const int* __restrict__ items,
                                              const int* __restrict__ mh,
                                              const int* __restrict__ mr,
                                              const int* __restrict__ mt,
                                              const float* __restrict__ GI,
                                              const float* __restrict__ whh,
                                              const float* __restrict__ bhh,
                                              const float* __restrict__ relnorm,
                                              float* __restrict__ ys0,
                                              float* __restrict__ hfin,
                                              float* __restrict__ o0,
                                              float* __restrict__ kge_part,   // [NB][2]
                                              float* __restrict__ l2_part)    // [NB]
{
    __shared__ __align__(16) float gibuf[2][CH * G3];   // 48 KiB
    __shared__ float logits[NM], probs[NM], opart[4][DIM], wred[4][4];

    if (blockIdx.x == 0) {
        gru_scan_staged(gibuf, GI, whh, bhh, nullptr, ys0, hfin);
        return;
    }

    const int b = blockIdx.x - 1;
    const int tid = threadIdx.x, lane = tid & 63, wave = tid >> 6;

    float iv = E[items[b] * DIM + lane];
    float kge0 = 0.0f, kge1 = 0.0f, l2acc = 0.0f, r2acc = 0.0f;

    for (int mm = 0; mm < 8; ++mm) {
        const int m = wave * 8 + mm;
        const int base = b * NM + m;                 // hop 0
        const int hidx = mh[base], ridx = mr[base], tidx = mt[base];
        float hv = E[hidx * DIM + lane];
        float tv = E[tidx * DIM + lane];
        l2acc = fmaf(hv, hv, l2acc);
        l2acc = fmaf(tv, tv, l2acc);
        r2acc += relnorm[ridx];
        const float* R = Rel + ridx * DIM * DIM;
        float accA = 0.0f, accK = 0.0f;
#pragma unroll 4
        for (int i = 0; i < DIM; ++i) {
            float rv = R[i * DIM + lane];
            accA = fmaf(bcast(iv, i), rv, accA);
            accK = fmaf(bcast(hv, i), rv, accK);
        }
        float la = wave_sum(accA * hv);              // item^T R h
        float lk = wave_sum(accK * tv);              // h^T R t
        if (lane == 0) logits[m] = la;
        kge0 += sigmoidf_(lk);
    }
    for (int mm = 0; mm < 8; ++mm) {
        const int m = wave * 8 + mm;
        const int base = NB * NM + b * NM + m;       // hop 1
        const int hidx = mh[base], ridx = mr[base], tidx = mt[base];
        float hv = E[hidx * DIM + lane];
        float tv = E[tidx * DIM + lane];
        l2acc = fmaf(hv, hv, l2acc);
        l2acc = fmaf(tv, tv, l2acc);
        r2acc += relnorm[ridx];
        const float* R = Rel + ridx * DIM * DIM;
        float accK = 0.0f;
#pragma unroll 4
        for (int i = 0; i < DIM; ++i)
            accK = fmaf(bcast(hv, i), R[i * DIM + lane], accK);
        kge1 += sigmoidf_(wave_sum(accK * tv));
    }
    __syncthreads();

    if (wave == 0) {
        float v = (lane < NM) ? logits[lane] : -1e30f;
        float mx = wave_max(v);
        float e = (lane < NM) ? __expf(v - mx) : 0.0f;
        float ssum = wave_sum(e);
        if (lane < NM) probs[lane] = e / ssum;
    }
    __syncthreads();

    float od = 0.0f;
    for (int mm = 0; mm < 8; ++mm) {
        const int m = wave * 8 + mm;
        const int tidx = mt[b * NM + m];
        od = fmaf(probs[m], E[tidx * DIM + lane], od);
    }
    opart[wave][lane] = od;
    float l2tot = wave_sum(l2acc);
    if (lane == 0) { wred[wave][0] = kge0; wred[wave][1] = kge1; wred[wave][2] = l2tot + r2acc; }
    __syncthreads();
    if (wave == 0)
        o0[b * DIM + lane] = opart[0][lane] + opart[1][lane] + opart[2][lane] + opart[3][lane];
    if (tid == 0) {
        kge_part[b * 2 + 0] = wred[0][0] + wred[1][0] + wred[2][0] + wred[3][0];
        kge_part[b * 2 + 1] = wred[0][1] + wred[1][1] + wred[2][1] + wred[3][1];
        l2_part[b]          = wred[0][2] + wred[1][2] + wred[2][2] + wred[3][2];
    }
}

// ---------- fused1: block 0 = GRU hop1 (staged); blocks 1..512 = att hop1 + o_sum ----------

__global__ __launch_bounds__(256, 1) void fused1(const float* __restrict__ E,
                                              const float* __restrict__ Rel,
                                              const int* __restrict__ mh,
                                              const int* __restrict__ mr,
                                              const int* __restrict__ mt,
                                              const float* __restrict__ GI,
                                              const float* __restrict__ whh,
                                              const float* __restrict__ bhh,
                                              const float* __restrict__ hfin,
                                              const float* __restrict__ ys0,
                                              float* __restrict__ ys1,
                                              const float* __restrict__ o0,
                                              float* __restrict__ osum)
{
    __shared__ __align__(16) float gibuf[2][CH * G3];   // 48 KiB
    __shared__ float logits[NM], probs[NM], opart[4][DIM];

    if (blockIdx.x == 0) {
        gru_scan_staged(gibuf, GI, whh, bhh, hfin, ys1, nullptr);
        return;
    }

    const int b = blockIdx.x - 1;
    const int tid = threadIdx.x, lane = tid & 63, wave = tid >> 6;

    float iv = ys0[b * DIM + lane];   // item_emb after 1 GRU pass

    for (int mm = 0; mm < 8; ++mm) {
        const int m = wave * 8 + mm;
        const int base = NB * NM + b * NM + m;       // hop 1
        const int hidx = mh[base], ridx = mr[base];
        float hv = E[hidx * DIM + lane];
        const float* R = Rel + ridx * DIM * DIM;
        float accA = 0.0f;
#pragma unroll 4
        for (int i = 0; i < DIM; ++i)
            accA = fmaf(bcast(iv, i), R[i * DIM + lane], accA);
        float la = wave_sum(accA * hv);
        if (lane == 0) logits[m] = la;
    }
    __syncthreads();
    if (wave == 0) {
        float v = (lane < NM) ? logits[lane] : -1e30f;
        float mx = wave_max(v);
        float e = (lane < NM) ? __expf(v - mx) : 0.0f;
        float ssum = wave_sum(e);
        if (lane < NM) probs[lane] = e / ssum;
    }
    __syncthreads();
    float od = 0.0f;
    for (int mm = 0; mm < 8; ++mm) {
        const int m = wave * 8 + mm;
        const int tidx = mt[NB * NM + b * NM + m];
        od = fmaf(probs[m], E[tidx * DIM + lane], od);
    }
    opart[wave][lane] = od;
    __syncthreads();
    if (wave == 0)
        osum[b * DIM + lane] = o0[b * DIM + lane] +
            opart[0][lane] + opart[1][lane] + opart[2][lane] + opart[3][lane];
}

// ---------- finalize: scores + losses ----------

__global__ __launch_bounds__(512) void finalize(const float* __restrict__ ys1,
                                                const float* __restrict__ osum,
                                                const int* __restrict__ labels,
                                                const float* __restrict__ kge_part,
                                                const float* __restrict__ l2_part,
                                                float* __restrict__ out)
{
    __shared__ float red[512];
    const int tid = threadIdx.x;

    float dot = 0.0f;
    const float* a = ys1 + tid * DIM;
    const float* c = osum + tid * DIM;
#pragma unroll 8
    for (int k = 0; k < DIM; ++k) dot = fmaf(a[k], c[k], dot);
    float score = sigmoidf_(dot);
    out[tid] = score;

    float s = fminf(fmaxf(score, EPSC), 1.0f - EPSC);
    float term = labels[tid] ? logf(s) : log1pf(-s);

    float bsum, ksum, lsum;
    {
        red[tid] = term; __syncthreads();
#pragma unroll
        for (int st = 256; st > 0; st >>= 1) { if (tid < st) red[tid] += red[tid + st]; __syncthreads(); }
        bsum = red[0]; __syncthreads();
    }
    {
        red[tid] = kge_part[2 * tid] + kge_part[2 * tid + 1]; __syncthreads();
#pragma unroll
        for (int st = 256; st > 0; st >>= 1) { if (tid < st) red[tid] += red[tid + st]; __syncthreads(); }
        ksum = red[0]; __syncthreads();
    }
    {
        red[tid] = l2_part[tid]; __syncthreads();
#pragma unroll
        for (int st = 256; st > 0; st >>= 1) { if (tid < st) red[tid] += red[tid + st]; __syncthreads(); }
        lsum = red[0];
    }

    if (tid == 0) {
        float base = -bsum / (float)NB;
        float kge  = -KGE_W * ksum / (float)(NB * NM);
        float l2   = L2_W * lsum;
        out[NB + 0] = base;
        out[NB + 1] = kge;
        out[NB + 2] = l2;
        out[NB + 3] = base + kge + l2;
    }
}

// ---------- host ----------

extern "C" void kernel_launch(void* const* d_in, const int* in_sizes, int n_in,
                              void* d_out, int out_size, void* d_ws, size_t ws_size,
                              hipStream_t stream) {
    const int*   items  = (const int*)d_in[0];
    const int*   labels = (const int*)d_in[1];
    const int*   mh     = (const int*)d_in[2];
    const int*   mr     = (const int*)d_in[3];
    const int*   mt     = (const int*)d_in[4];
    const float* E      = (const float*)d_in[5];
    const float* Rel    = (const float*)d_in[6];
    const float* wih    = (const float*)d_in[7];
    const float* whh    = (const float*)d_in[8];
    const float* bih    = (const float*)d_in[9];
    const float* bhh    = (const float*)d_in[10];
    float* out = (float*)d_out;
    float* ws  = (float*)d_ws;

    // workspace layout (floats)
    float* GI0     = ws;                 // 512*192 = 98304
    float* GI1     = GI0 + 98304;        // 98304
    float* ys0     = GI1 + 98304;        // 32768
    float* ys1     = ys0 + 32768;        // 32768
    float* hfin    = ys1 + 32768;        // 64
    float* o0      = hfin + 64;          // 32768
    float* osum    = o0 + 32768;         // 32768
    float* relnorm = osum + 32768;       // 32
    float* kge_p   = relnorm + 32;       // 1024
    float* l2_p    = kge_p + 1024;       // 512

    // gi0: GI for hop 0 (x = entity_emb[items]) + per-relation sqnorms
    gi_kernel<<<NB + NRELS, 64, 0, stream>>>(E, items, wih, bih, Rel, GI0, relnorm);
    // fused0: GRU hop0 (block 0, LDS-staged GI) || attention hop0 + KGE + L2
    fused0<<<NB + 1, 256, 0, stream>>>(E, Rel, items, mh, mr, mt, GI0, whh, bhh,
                                       relnorm, ys0, hfin, o0, kge_p, l2_p);
    // gi1: GI for hop 1 (x = ys0)
    gi_kernel<<<NB, 64, 0, stream>>>(ys0, nullptr, wih, bih, Rel, GI1, relnorm);
    // fused1: GRU hop1 (block 0, LDS-staged GI) || attention hop1 + o_sum
    fused1<<<NB + 1, 256, 0, stream>>>(E, Rel, mh, mr, mt, GI1, whh, bhh, hfin,
                                       ys0, ys1, o0, osum);
    // finalize: scores + losses
    finalize<<<1, 512, 0, stream>>>(ys1, osum, labels, kge_p, l2_p, out);
}

// Round 10
// 477.093 us; speedup vs baseline: 1.5569x; 1.1148x over previous
//
#include <hip/hip_runtime.h>

#define DIM   64
#define G3    192      // 3*DIM
#define NB    512      // BATCH
#define NM    32       // N_MEM
#define NRELS 32
#define CH    32       // GI chunk (steps) staged in LDS
#define NCH   (NB/CH)
#define KGE_W 0.01f
#define L2_W  1e-7f
#define EPSC  1e-7f

// ---------- helpers ----------

__device__ inline float bcast(float v, int srclane) {
    return __int_as_float(__builtin_amdgcn_readlane(__float_as_int(v), srclane));
}

__device__ inline float sigmoidf_(float x) { return 1.0f / (1.0f + __expf(-x)); }
__device__ inline float tanhf_(float x)    { return 1.0f - 2.0f / (1.0f + __expf(2.0f * x)); }

__device__ inline float wave_sum(float v) {
#pragma unroll
    for (int off = 32; off > 0; off >>= 1) v += __shfl_xor(v, off, 64);
    return v;
}
__device__ inline float wave_max(float v) {
#pragma unroll
    for (int off = 32; off > 0; off >>= 1) v = fmaxf(v, __shfl_xor(v, off, 64));
    return v;
}

// ---------- X-macros ----------

#define FOR32(F) F(0)F(1)F(2)F(3)F(4)F(5)F(6)F(7)F(8)F(9)F(10)F(11)F(12)F(13)F(14)F(15) \
                 F(16)F(17)F(18)F(19)F(20)F(21)F(22)F(23)F(24)F(25)F(26)F(27)F(28)F(29)F(30)F(31)
#define FOR16A(F) F(0)F(1)F(2)F(3)F(4)F(5)F(6)F(7)F(8)F(9)F(10)F(11)F(12)F(13)F(14)F(15)
#define FOR16B(F) F(16)F(17)F(18)F(19)F(20)F(21)F(22)F(23)F(24)F(25)F(26)F(27)F(28)F(29)F(30)F(31)

// f32 -> f16 (RTE) bit pattern
#define F16U(x) ((unsigned)__builtin_bit_cast(unsigned short, (_Float16)(x)))

// ---------- GRU with LDS-staged GI + inline-asm v_dot2_f32_f16 matvec ----------
// Block 0 only. Wave 0 runs the serial recurrence: whh as 96 packed f16x2
// VGPRs (pairs along k); h packed to f16 pairs once per step (verified R8
// shuffle code); 32 batched v_readlane -> SGPRs; 96 v_dot2_f32_f16 (f32
// accumulate) in 6 interleaved chains. Waves 1-3 stage GI chunks to LDS.

__device__ __forceinline__ void gru_scan_staged(float (*gibuf)[CH * G3],   // [2][CH*192] LDS
                                                const float* __restrict__ GI,   // [NB][192]
                                                const float* __restrict__ whh,  // [192][64]
                                                const float* __restrict__ bhh,  // [192]
                                                const float* __restrict__ h0,   // [64] or nullptr
                                                float* __restrict__ ys,         // [NB][64]
                                                float* __restrict__ hfin_out)   // [64] or nullptr
{
    const int tid  = threadIdx.x;
    const int lane = tid & 63;
    const int wave = tid >> 6;

    // prologue: stage chunk 0 into buffer 0
    if (wave != 0) {
        const int sid = tid - 64;                    // 0..191
        const float4* src = (const float4*)GI;
        float4* dst = (float4*)gibuf[0];
#pragma unroll
        for (int j = 0; j < 8; ++j) dst[sid + j * 192] = src[sid + j * 192];
    }
    __syncthreads();

    if (wave == 0) {
        const float* wrp = whh + (0 * DIM + lane) * DIM;
        const float* wzp = whh + (1 * DIM + lane) * DIM;
        const float* wnp = whh + (2 * DIM + lane) * DIM;

        // 96 packed f16x2 weight pairs (pairs along k)
#define DWP(j) unsigned uwr##j, uwz##j, uwn##j;
        FOR32(DWP)
#undef DWP
#define LWP(j) uwr##j = F16U(wrp[2*(j)]) | (F16U(wrp[2*(j)+1]) << 16); \
               uwz##j = F16U(wzp[2*(j)]) | (F16U(wzp[2*(j)+1]) << 16); \
               uwn##j = F16U(wnp[2*(j)]) | (F16U(wnp[2*(j)+1]) << 16);
        FOR32(LWP)
#undef LWP

        const float br = bhh[lane], bz = bhh[DIM + lane], bn = bhh[2 * DIM + lane];
        float h = h0 ? h0[lane] : 0.0f;

        for (int c = 0; c < NCH; ++c) {
            const float* buf = gibuf[c & 1];
            for (int tl = 0; tl < CH; ++tl) {
                const float* gi = buf + tl * G3;
                float c0 = gi[lane], c1 = gi[DIM + lane], c2 = gi[2 * DIM + lane];  // ds_read

                // pack h into f16 pairs: lane j (j<32) holds (h_2j, h_2j+1)
                unsigned short hu = __builtin_bit_cast(unsigned short, (_Float16)h);
                int lo = __shfl((int)(unsigned)hu, (2 * lane) & 63);
                int hi = __shfl((int)(unsigned)hu, (2 * lane + 1) & 63);
                unsigned packed = ((unsigned)lo & 0xffffu) | ((unsigned)hi << 16);

                // batch all 32 broadcasts into SGPRs first (hazard-safe spacing)
#define RL(j) unsigned hp##j = (unsigned)__builtin_amdgcn_readlane((int)packed, j);
                FOR32(RL)
#undef RL

                float ar0 = 0.f, ar1 = 0.f, az0 = 0.f, az1 = 0.f, an0 = 0.f, an1 = 0.f;
#define SJ0(j) { asm("v_dot2_f32_f16 %0, %1, %2, %0" : "+v"(ar0) : "v"(uwr##j), "s"(hp##j)); \
                 asm("v_dot2_f32_f16 %0, %1, %2, %0" : "+v"(az0) : "v"(uwz##j), "s"(hp##j)); \
                 asm("v_dot2_f32_f16 %0, %1, %2, %0" : "+v"(an0) : "v"(uwn##j), "s"(hp##j)); }
                FOR16A(SJ0)
#undef SJ0
#define SJ1(j) { asm("v_dot2_f32_f16 %0, %1, %2, %0" : "+v"(ar1) : "v"(uwr##j), "s"(hp##j)); \
                 asm("v_dot2_f32_f16 %0, %1, %2, %0" : "+v"(az1) : "v"(uwz##j), "s"(hp##j)); \
                 asm("v_dot2_f32_f16 %0, %1, %2, %0" : "+v"(an1) : "v"(uwn##j), "s"(hp##j)); }
                FOR16B(SJ1)
#undef SJ1

                float ghr = (ar0 + ar1) + br;
                float ghz = (az0 + az1) + bz;
                float ghn = (an0 + an1) + bn;

                float r = sigmoidf_(c0 + ghr);
                float z = sigmoidf_(c1 + ghz);
                float n = tanhf_(c2 + r * ghn);
                h = n + z * (h - n);               // (1-z)*n + z*h

                ys[(c * CH + tl) * DIM + lane] = h;
            }
            __syncthreads();                        // chunk boundary
        }
        if (hfin_out) hfin_out[lane] = h;
    } else {
        const int sid = tid - 64;                    // 0..191
        for (int c = 0; c < NCH; ++c) {
            if (c + 1 < NCH) {
                const float4* src = (const float4*)(GI + (size_t)(c + 1) * CH * G3);
                float4* dst = (float4*)gibuf[(c + 1) & 1];
#pragma unroll
                for (int j = 0; j < 8; ++j) dst[sid + j * 192] = src[sid + j * 192];
            }
            __syncthreads();
        }
    }
}

// ---------- gi: GI = wih @ x + bih (+ per-relation sqnorm on extra blocks) ----------

__global__ __launch_bounds__(64) void gi_kernel(const float* __restrict__ xsrc,
                                                const int* __restrict__ idx,    // nullptr => direct
                                                const float* __restrict__ wih,  // [192][64]
                                                const float* __restrict__ bih,  // [192]
                                                const float* __restrict__ Rel,  // [32][4096]
                                                float* __restrict__ GI,         // [NB][192]
                                                float* __restrict__ relnorm)    // [32]
{
    const int blk = blockIdx.x, lane = threadIdx.x;
    if (blk >= NB) {
        const int r = blk - NB;
        const float* R = Rel + r * DIM * DIM;
        float a = 0.0f;
#pragma unroll 4
        for (int i = 0; i < DIM; ++i) { float v = R[i * DIM + lane]; a = fmaf(v, v, a); }
        a = wave_sum(a);
        if (lane == 0) relnorm[r] = a;
        return;
    }
    const int b = blk;
    float xv = idx ? xsrc[idx[b] * DIM + lane] : xsrc[b * DIM + lane];
    float a0 = bih[lane], a1 = bih[DIM + lane], a2 = bih[2 * DIM + lane];
    const float* w0 = wih + (0 * DIM + lane) * DIM;
    const float* w1 = wih + (1 * DIM + lane) * DIM;
    const float* w2 = wih + (2 * DIM + lane) * DIM;
#pragma unroll 4
    for (int k = 0; k < DIM; ++k) {
        float xk = bcast(xv, k);
        a0 = fmaf(w0[k], xk, a0);
        a1 = fmaf(w1[k], xk, a1);
        a2 = fmaf(w2[k], xk, a2);
    }
    float* gp = GI + b * G3;
    gp[lane] = a0; gp[DIM + lane] = a1; gp[2 * DIM + lane] = a2;
}

// ---------- fused0: block 0 = GRU hop0 (staged); blocks 1..512 = att hop0 + KGE + L2 ----------

__global__ __launch_bounds__(256, 1) void fused0(const float* __restrict__ E,
                                              const float* __restrict__ Rel,
                                              const int* __restrict__ items,
                                              const int* __restrict__ mh,
                                              const int* __restrict__ mr,
                                              const int* __restrict__ mt,
                                              const float* __restrict__ GI,
                                              const float* __restrict__ whh,
                                              const float* __restrict__ bhh,
                                              const float* __restrict__ relnorm,
                                              float* __restrict__ ys0,
                                              float* __restrict__ hfin,
                                              float* __restrict__ o0,
                                              float* __restrict__ kge_part,   // [NB][2]
                                              float* __restrict__ l2_part)    // [NB]
{
    __shared__ __align__(16) float gibuf[2][CH * G3];   // 48 KiB
    __shared__ float logits[NM], probs[NM], opart[4][DIM], wred[4][4];

    if (blockIdx.x == 0) {
        gru_scan_staged(gibuf, GI, whh, bhh, nullptr, ys0, hfin);
        return;
    }

    const int b = blockIdx.x - 1;
    const int tid = threadIdx.x, lane = tid & 63, wave = tid >> 6;

    float iv = E[items[b] * DIM + lane];
    float kge0 = 0.0f, kge1 = 0.0f, l2acc = 0.0f, r2acc = 0.0f;

    for (int mm = 0; mm < 8; ++mm) {
        const int m = wave * 8 + mm;
        const int base = b * NM + m;                 // hop 0
        const int hidx = mh[base], ridx = mr[base], tidx = mt[base];
        float hv = E[hidx * DIM + lane];
        float tv = E[tidx * DIM + lane];
        l2acc = fmaf(hv, hv, l2acc);
        l2acc = fmaf(tv, tv, l2acc);
        r2acc += relnorm[ridx];
        const float* R = Rel + ridx * DIM * DIM;
        float accA = 0.0f, accK = 0.0f;
#pragma unroll 4
        for (int i = 0; i < DIM; ++i) {
            float rv = R[i * DIM + lane];
            accA = fmaf(bcast(iv, i), rv, accA);
            accK = fmaf(bcast(hv, i), rv, accK);
        }
        float la = wave_sum(accA * hv);              // item^T R h
        float lk = wave_sum(accK * tv);              // h^T R t
        if (lane == 0) logits[m] = la;
        kge0 += sigmoidf_(lk);
    }
    for (int mm = 0; mm < 8; ++mm) {
        const int m = wave * 8 + mm;
        const int base = NB * NM + b * NM + m;       // hop 1
        const int hidx = mh[base], ridx = mr[base], tidx = mt[base];
        float hv = E[hidx * DIM + lane];
        float tv = E[tidx * DIM + lane];
        l2acc = fmaf(hv, hv, l2acc);
        l2acc = fmaf(tv, tv, l2acc);
        r2acc += relnorm[ridx];
        const float* R = Rel + ridx * DIM * DIM;
        float accK = 0.0f;
#pragma unroll 4
        for (int i = 0; i < DIM; ++i)
            accK = fmaf(bcast(hv, i), R[i * DIM + lane], accK);
        kge1 += sigmoidf_(wave_sum(accK * tv));
    }
    __syncthreads();

    if (wave == 0) {
        float v = (lane < NM) ? logits[lane] : -1e30f;
        float mx = wave_max(v);
        float e = (lane < NM) ? __expf(v - mx) : 0.0f;
        float ssum = wave_sum(e);
        if (lane < NM) probs[lane] = e / ssum;
    }
    __syncthreads();

    float od = 0.0f;
    for (int mm = 0; mm < 8; ++mm) {
        const int m = wave * 8 + mm;
        const int tidx = mt[b * NM + m];
        od = fmaf(probs[m], E[tidx * DIM + lane], od);
    }
    opart[wave][lane] = od;
    float l2tot = wave_sum(l2acc);
    if (lane == 0) { wred[wave][0] = kge0; wred[wave][1] = kge1; wred[wave][2] = l2tot + r2acc; }
    __syncthreads();
    if (wave == 0)
        o0[b * DIM + lane] = opart[0][lane] + opart[1][lane] + opart[2][lane] + opart[3][lane];
    if (tid == 0) {
        kge_part[b * 2 + 0] = wred[0][0] + wred[1][0] + wred[2][0] + wred[3][0];
        kge_part[b * 2 + 1] = wred[0][1] + wred[1][1] + wred[2][1] + wred[3][1];
        l2_part[b]          = wred[0][2] + wred[1][2] + wred[2][2] + wred[3][2];
    }
}

// ---------- fused1: block 0 = GRU hop1 (staged); blocks 1..512 = att hop1 + o_sum ----------

__global__ __launch_bounds__(256, 1) void fused1(const float* __restrict__ E,
                                              const float* __restrict__ Rel,
                                              const int* __restrict__ mh,
                                              const int* __restrict__ mr,
                                              const int* __restrict__ mt,
                                              const float* __restrict__ GI,
                                              const float* __restrict__ whh,
                                              const float* __restrict__ bhh,
                                              const float* __restrict__ hfin,
                                              const float* __restrict__ ys0,
                                              float* __restrict__ ys1,
                                              const float* __restrict__ o0,
                                              float* __restrict__ osum)
{
    __shared__ __align__(16) float gibuf[2][CH * G3];   // 48 KiB
    __shared__ float logits[NM], probs[NM], opart[4][DIM];

    if (blockIdx.x == 0) {
        gru_scan_staged(gibuf, GI, whh, bhh, hfin, ys1, nullptr);
        return;
    }

    const int b = blockIdx.x - 1;
    const int tid = threadIdx.x, lane = tid & 63, wave = tid >> 6;

    float iv = ys0[b * DIM + lane];   // item_emb after 1 GRU pass

    for (int mm = 0; mm < 8; ++mm) {
        const int m = wave * 8 + mm;
        const int base = NB * NM + b * NM + m;       // hop 1
        const int hidx = mh[base], ridx = mr[base];
        float hv = E[hidx * DIM + lane];
        const float* R = Rel + ridx * DIM * DIM;
        float accA = 0.0f;
#pragma unroll 4
        for (int i = 0; i < DIM; ++i)
            accA = fmaf(bcast(iv, i), R[i * DIM + lane], accA);
        float la = wave_sum(accA * hv);
        if (lane == 0) logits[m] = la;
    }
    __syncthreads();
    if (wave == 0) {
        float v = (lane < NM) ? logits[lane] : -1e30f;
        float mx = wave_max(v);
        float e = (lane < NM) ? __expf(v - mx) : 0.0f;
        float ssum = wave_sum(e);
        if (lane < NM) probs[lane] = e / ssum;
    }
    __syncthreads();
    float od = 0.0f;
    for (int mm = 0; mm < 8; ++mm) {
        const int m = wave * 8 + mm;
        const int tidx = mt[NB * NM + b * NM + m];
        od = fmaf(probs[m], E[tidx * DIM + lane], od);
    }
    opart[wave][lane] = od;
    __syncthreads();
    if (wave == 0)
        osum[b * DIM + lane] = o0[b * DIM + lane] +
            opart[0][lane] + opart[1][lane] + opart[2][lane] + opart[3][lane];
}

// ---------- finalize: scores + losses ----------

__global__ __launch_bounds__(512) void finalize(const float* __restrict__ ys1,
                                                const float* __restrict__ osum,
                                                const int* __restrict__ labels,
                                                const float* __restrict__ kge_part,
                                                const float* __restrict__ l2_part,
                                                float* __restrict__ out)
{
    __shared__ float red[512];
    const int tid = threadIdx.x;

    float dot = 0.0f;
    const float* a = ys1 + tid * DIM;
    const float* c = osum + tid * DIM;
#pragma unroll 8
    for (int k = 0; k < DIM; ++k) dot = fmaf(a[k], c[k], dot);
    float score = sigmoidf_(dot);
    out[tid] = score;

    float s = fminf(fmaxf(score, EPSC), 1.0f - EPSC);
    float term = labels[tid] ? logf(s) : log1pf(-s);

    float bsum, ksum, lsum;
    {
        red[tid] = term; __syncthreads();
#pragma unroll
        for (int st = 256; st > 0; st >>= 1) { if (tid < st) red[tid] += red[tid + st]; __syncthreads(); }
        bsum = red[0]; __syncthreads();
    }
    {
        red[tid] = kge_part[2 * tid] + kge_part[2 * tid + 1]; __syncthreads();
#pragma unroll
        for (int st = 256; st > 0; st >>= 1) { if (tid < st) red[tid] += red[tid + st]; __syncthreads(); }
        ksum = red[0]; __syncthreads();
    }
    {
        red[tid] = l2_part[tid]; __syncthreads();
#pragma unroll
        for (int st = 256; st > 0; st >>= 1) { if (tid < st) red[tid] += red[tid + st]; __syncthreads(); }
        lsum = red[0];
    }

    if (tid == 0) {
        float base = -bsum / (float)NB;
        float kge  = -KGE_W * ksum / (float)(NB * NM);
        float l2   = L2_W * lsum;
        out[NB + 0] = base;
        out[NB + 1] = kge;
        out[NB + 2] = l2;
        out[NB + 3] = base + kge + l2;
    }
}

// ---------- host ----------

extern "C" void kernel_launch(void* const* d_in, const int* in_sizes, int n_in,
                              void* d_out, int out_size, void* d_ws, size_t ws_size,
                              hipStream_t stream) {
    const int*   items  = (const int*)d_in[0];
    const int*   labels = (const int*)d_in[1];
    const int*   mh     = (const int*)d_in[2];
    const int*   mr     = (const int*)d_in[3];
    const int*   mt     = (const int*)d_in[4];
    const float* E      = (const float*)d_in[5];
    const float* Rel    = (const float*)d_in[6];
    const float* wih    = (const float*)d_in[7];
    const float* whh    = (const float*)d_in[8];
    const float* bih    = (const float*)d_in[9];
    const float* bhh    = (const float*)d_in[10];
    float* out = (float*)d_out;
    float* ws  = (float*)d_ws;

    // workspace layout (floats)
    float* GI0     = ws;                 // 512*192 = 98304
    float* GI1     = GI0 + 98304;        // 98304
    float* ys0     = GI1 + 98304;        // 32768
    float* ys1     = ys0 + 32768;        // 32768
    float* hfin    = ys1 + 32768;        // 64
    float* o0      = hfin + 64;          // 32768
    float* osum    = o0 + 32768;         // 32768
    float* relnorm = osum + 32768;       // 32
    float* kge_p   = relnorm + 32;       // 1024
    float* l2_p    = kge_p + 1024;       // 512

    // gi0: GI for hop 0 (x = entity_emb[items]) + per-relation sqnorms
    gi_kernel<<<NB + NRELS, 64, 0, stream>>>(E, items, wih, bih, Rel, GI0, relnorm);
    // fused0: GRU hop0 (block 0, LDS-staged GI, dot2 matvec) || att hop0 + KGE + L2
    fused0<<<NB + 1, 256, 0, stream>>>(E, Rel, items, mh, mr, mt, GI0, whh, bhh,
                                       relnorm, ys0, hfin, o0, kge_p, l2_p);
    // gi1: GI for hop 1 (x = ys0)
    gi_kernel<<<NB, 64, 0, stream>>>(ys0, nullptr, wih, bih, Rel, GI1, relnorm);
    // fused1: GRU hop1 (block 0, LDS-staged GI, dot2 matvec) || att hop1 + o_sum
    fused1<<<NB + 1, 256, 0, stream>>>(E, Rel, mh, mr, mt, GI1, whh, bhh, hfin,
                                       ys0, ys1, o0, osum);
    // finalize: scores + losses
    finalize<<<1, 512, 0, stream>>>(ys1, osum, labels, kge_p, l2_p, out);
}